// Round 2
// baseline (4847.924 us; speedup 1.0000x reference)
//
#include <hip/hip_runtime.h>
#include <math.h>

// Problem constants (per batch): C=64, H=W=256, P=65536 pixels.
#define P_ 65536

// ---- per-batch workspace layout (float offsets). Peak = 33,423,360 floats
// ---- = 127.5 MiB. Buffers time-shared across stages; batches loop serially.
#define DW_OFF   0ul            // 192*P = 12,582,912 fl (q,k,v post-dwconv)
#define QKV_OFF  12582912ul     // 192*P (pre-dwconv)
#define Y_OFF    25165824ul     // 64*P  = 4,194,304 fl (LN out / attn out)
#define ATTP_OFF 29360128ul     // 4*P   = 262,144 fl (K-split partials)
#define ATT_OFF  29622272ul     // P     = 65,536 fl (softmaxed attention)
// stage C overlays:
#define HID_OFF  0ul            // 340*P = 22,282,240 fl
#define Y2_OFF   22282240ul     // 64*P (LN out; dead before G written)
#define G_OFF    22282240ul     // 170*P = 11,141,120 fl (overlays dead Y2)

// ---------------- LayerNorm over channel dim (per pixel, 64 channels) -------
__global__ __launch_bounds__(256) void ln_kernel(const float* __restrict__ x,
        const float* __restrict__ w, const float* __restrict__ b,
        float* __restrict__ y) {
    int hw = blockIdx.x * 256 + threadIdx.x;   // [0, P_)
    const float* xp = x + hw;
    float v[64];
    float s = 0.f;
    #pragma unroll
    for (int c = 0; c < 64; ++c) { v[c] = xp[(size_t)c * P_]; s += v[c]; }
    float mu = s * (1.0f / 64.0f);
    float s2 = 0.f;
    #pragma unroll
    for (int c = 0; c < 64; ++c) { float d = v[c] - mu; s2 += d * d; }
    float inv = rsqrtf(s2 * (1.0f / 64.0f) + 1e-5f);
    float* yp = y + hw;
    #pragma unroll
    for (int c = 0; c < 64; ++c)
        yp[(size_t)c * P_] = (v[c] - mu) * inv * w[c] + b[c];
}

// ---------------- 1x1 conv (pointwise GEMM), optional residual --------------
// 64-pixel tile staged in LDS; thread = (pixel-group of 4, o-group of 4).
template<int CIN>
__global__ __launch_bounds__(256) void conv1x1_kernel(const float* __restrict__ in,
        const float* __restrict__ Wt, const float* __restrict__ bias,
        float* __restrict__ out, const float* __restrict__ res, int Cout) {
    extern __shared__ float lds[];           // [CIN][64]
    int hw0 = blockIdx.x * 64;               // [0, P_)
    int tid = threadIdx.x;
    for (int idx = tid; idx < CIN * 64; idx += 256) {
        int c = idx >> 6, pp = idx & 63;
        lds[idx] = in[(size_t)c * P_ + hw0 + pp];
    }
    __syncthreads();
    int pg = tid & 15, og = tid >> 4;
    const float4* lds4 = (const float4*)lds;
    for (int o0 = og * 4; o0 < Cout; o0 += 64) {
        float4 acc0, acc1, acc2, acc3;
        { float bv = bias[o0+0]; acc0 = make_float4(bv,bv,bv,bv); }
        { float bv = bias[o0+1]; acc1 = make_float4(bv,bv,bv,bv); }
        { float bv = bias[o0+2]; acc2 = make_float4(bv,bv,bv,bv); }
        { float bv = bias[o0+3]; acc3 = make_float4(bv,bv,bv,bv); }
        const float* w0p = Wt + (size_t)(o0+0) * CIN;
        const float* w1p = Wt + (size_t)(o0+1) * CIN;
        const float* w2p = Wt + (size_t)(o0+2) * CIN;
        const float* w3p = Wt + (size_t)(o0+3) * CIN;
        #pragma unroll 8
        for (int c = 0; c < CIN; ++c) {
            float4 iv = lds4[c * 16 + pg];
            float wa = w0p[c], wb = w1p[c], wc = w2p[c], wd = w3p[c];
            acc0.x += wa*iv.x; acc0.y += wa*iv.y; acc0.z += wa*iv.z; acc0.w += wa*iv.w;
            acc1.x += wb*iv.x; acc1.y += wb*iv.y; acc1.z += wb*iv.z; acc1.w += wb*iv.w;
            acc2.x += wc*iv.x; acc2.y += wc*iv.y; acc2.z += wc*iv.z; acc2.w += wc*iv.w;
            acc3.x += wd*iv.x; acc3.y += wd*iv.y; acc3.z += wd*iv.z; acc3.w += wd*iv.w;
        }
        float4 accs[4] = {acc0, acc1, acc2, acc3};
        #pragma unroll
        for (int i = 0; i < 4; ++i) {
            size_t ob = (size_t)(o0+i) * P_ + hw0 + pg*4;
            float4 r = accs[i];
            if (res) {
                float4 rv = *(const float4*)(res + ob);
                r.x += rv.x; r.y += rv.y; r.z += rv.z; r.w += rv.w;
            }
            *(float4*)(out + ob) = r;
        }
    }
}

// ---------------- depthwise 3x3 conv (SAME, zero pad) + bias ----------------
__global__ __launch_bounds__(256) void dwconv_kernel(const float* __restrict__ in,
        const float* __restrict__ w9, const float* __restrict__ bias,
        float* __restrict__ out) {
    size_t t = (size_t)blockIdx.x * 256 + threadIdx.x;   // Cch*P_ threads
    int hw = (int)(t & 65535);
    int o = (int)(t >> 16);
    int h = hw >> 8, w = hw & 255;
    const float* ip = in + ((size_t)o << 16);
    const float* wp = w9 + o * 9;
    float acc = bias[o];
    #pragma unroll
    for (int dy = -1; dy <= 1; ++dy) {
        int hh = h + dy;
        if (hh < 0 || hh > 255) continue;
        #pragma unroll
        for (int dx = -1; dx <= 1; ++dx) {
            int ww = w + dx;
            if (ww < 0 || ww > 255) continue;
            acc += wp[(dy+1)*3 + (dx+1)] * ip[hh*256 + ww];
        }
    }
    out[t] = acc;
}

// ---------------- FFN depthwise 3x3 fused with exact-GELU gate --------------
__global__ __launch_bounds__(256) void ffn_dw_kernel(const float* __restrict__ hid,
        const float* __restrict__ w9, const float* __restrict__ bias,
        float* __restrict__ g) {
    size_t t = (size_t)blockIdx.x * 256 + threadIdx.x;   // 170*P_ threads
    int hw = (int)(t & 65535);
    int i = (int)(t >> 16);                  // [0,170)
    int h = hw >> 8, w = hw & 255;
    const float* ip1 = hid + ((size_t)i << 16);
    const float* ip2 = ip1 + ((size_t)170 << 16);
    const float* wp1 = w9 + i * 9;
    const float* wp2 = w9 + (i + 170) * 9;
    float a = bias[i], b2 = bias[i + 170];
    #pragma unroll
    for (int dy = -1; dy <= 1; ++dy) {
        int hh = h + dy;
        if (hh < 0 || hh > 255) continue;
        #pragma unroll
        for (int dx = -1; dx <= 1; ++dx) {
            int ww = w + dx;
            if (ww < 0 || ww > 255) continue;
            int off = hh*256 + ww;
            int ki = (dy+1)*3 + (dx+1);
            a  += wp1[ki] * ip1[off];
            b2 += wp2[ki] * ip2[off];
        }
    }
    float ge = 0.5f * a * (1.0f + erff(a * 0.70710678118654752440f));
    g[t] = ge * b2;
}

// ---------------- l2 normalize over W, per (ch<128, h) row ------------------
__global__ __launch_bounds__(256) void l2norm_w_kernel(float* __restrict__ dw) {
    int blk = blockIdx.x;                    // 128*256 blocks
    int h = blk & 255;
    int ch = blk >> 8;                       // [0,128): q then k
    float* row = dw + ((size_t)ch << 16) + h*256;
    int tid = threadIdx.x;
    float v = row[tid];
    float s = v * v;
    #pragma unroll
    for (int off = 32; off; off >>= 1) s += __shfl_down(s, off, 64);
    __shared__ float red[4];
    int wv = tid >> 6, ln = tid & 63;
    if (ln == 0) red[wv] = s;
    __syncthreads();
    float tot = red[0] + red[1] + red[2] + red[3];
    float dn = fmaxf(sqrtf(tot), 1e-12f);
    row[tid] = v / dn;
}

// ---------------- l2 normalize over (c,w), per (q|k, h) ---------------------
__global__ __launch_bounds__(256) void l2norm_h_kernel(float* __restrict__ dw) {
    int h = blockIdx.x, qk = blockIdx.y;
    float* base = dw + ((size_t)(qk*64) << 16) + h*256;
    int tid = threadIdx.x;
    float s = 0.f;
    for (int idx = tid; idx < 16384; idx += 256) {
        int c = idx >> 8, w = idx & 255;
        float v = base[((size_t)c << 16) + w];
        s += v * v;
    }
    #pragma unroll
    for (int off = 32; off; off >>= 1) s += __shfl_down(s, off, 64);
    __shared__ float red[4];
    int wv = tid >> 6, ln = tid & 63;
    if (ln == 0) red[wv] = s;
    __syncthreads();
    float tot = red[0] + red[1] + red[2] + red[3];
    float inv = 1.0f / fmaxf(sqrtf(tot), 1e-12f);
    for (int idx = tid; idx < 16384; idx += 256) {
        int c = idx >> 8, w = idx & 255;
        base[((size_t)c << 16) + w] *= inv;
    }
}

// ---------------- attention logits GEMM, K-split over channels --------------
// C[i,j] = sum_{c,r} Q[c][?][?] * K[c][?][?]; RCONTIG picks which spatial dim
// is the reduction. grid = (16 tiles, 4 ksplit). 64x64 tile, 4x4 micro-tile.
template<bool RCONTIG>
__global__ __launch_bounds__(256) void attn_gemm_kernel(const float* __restrict__ dw,
        float* __restrict__ part) {
    int tile = blockIdx.x, ks = blockIdx.y;
    int i0 = (tile & 3) * 64, j0 = (tile >> 2) * 64;
    const float* qb = dw;
    const float* kb = dw + ((size_t)64 << 16);
    __shared__ float Qt[16 * 68];
    __shared__ float Kt[16 * 68];
    int tid = threadIdx.x;
    int tx = tid & 15, ty = tid >> 4;
    float acc[4][4] = {{0.f}};
    for (int c = ks * 16; c < ks * 16 + 16; ++c) {
        const float* qc = qb + ((size_t)c << 16);
        const float* kc = kb + ((size_t)c << 16);
        for (int r0 = 0; r0 < 256; r0 += 16) {
            __syncthreads();
            #pragma unroll
            for (int rep = 0; rep < 4; ++rep) {
                int idx = tid + rep * 256;
                if (RCONTIG) {
                    int rr = idx & 15, ii = idx >> 4;       // lanes vary rr
                    Qt[rr*68 + ii] = qc[(i0+ii)*256 + r0+rr];
                    Kt[rr*68 + ii] = kc[(j0+ii)*256 + r0+rr];
                } else {
                    int ii = idx & 63, rr = idx >> 6;       // lanes vary ii
                    Qt[rr*68 + ii] = qc[(r0+rr)*256 + i0+ii];
                    Kt[rr*68 + ii] = kc[(r0+rr)*256 + j0+ii];
                }
            }
            __syncthreads();
            #pragma unroll
            for (int rr = 0; rr < 16; ++rr) {
                float4 qv = *(const float4*)&Qt[rr*68 + tx*4];
                float4 kv = *(const float4*)&Kt[rr*68 + ty*4];
                acc[0][0] += qv.x*kv.x; acc[0][1] += qv.x*kv.y; acc[0][2] += qv.x*kv.z; acc[0][3] += qv.x*kv.w;
                acc[1][0] += qv.y*kv.x; acc[1][1] += qv.y*kv.y; acc[1][2] += qv.y*kv.z; acc[1][3] += qv.y*kv.w;
                acc[2][0] += qv.z*kv.x; acc[2][1] += qv.z*kv.y; acc[2][2] += qv.z*kv.z; acc[2][3] += qv.z*kv.w;
                acc[3][0] += qv.w*kv.x; acc[3][1] += qv.w*kv.y; acc[3][2] += qv.w*kv.z; acc[3][3] += qv.w*kv.w;
            }
        }
    }
    size_t pb = (size_t)ks * 65536;
    #pragma unroll
    for (int a = 0; a < 4; ++a)
        #pragma unroll
        for (int b2 = 0; b2 < 4; ++b2)
            part[pb + (size_t)(i0 + tx*4 + a) * 256 + (j0 + ty*4 + b2)] = acc[a][b2];
}

// ---------------- sum K-split partials, scale by temp, softmax row ----------
__global__ __launch_bounds__(256) void softmax_kernel(const float* __restrict__ part,
        const float* __restrict__ temp, float* __restrict__ att) {
    int i = blockIdx.x;
    int j = threadIdx.x;
    size_t rowoff = (size_t)i * 256 + j;
    float s = part[0*65536 + rowoff] + part[1*65536 + rowoff]
            + part[2*65536 + rowoff] + part[3*65536 + rowoff];
    s *= temp[0];
    __shared__ float redA[4], redB[4];
    int wv = j >> 6, ln = j & 63;
    float m = s;
    #pragma unroll
    for (int off = 32; off; off >>= 1) m = fmaxf(m, __shfl_down(m, off, 64));
    if (ln == 0) redA[wv] = m;
    __syncthreads();
    m = fmaxf(fmaxf(redA[0], redA[1]), fmaxf(redA[2], redA[3]));
    float e = expf(s - m);
    float t2 = e;
    #pragma unroll
    for (int off = 32; off; off >>= 1) t2 += __shfl_down(t2, off, 64);
    if (ln == 0) redB[wv] = t2;
    __syncthreads();
    float tot = redB[0] + redB[1] + redB[2] + redB[3];
    att[rowoff] = e / tot;
}

// ---------------- out[c,h,u] = sum_w v[c,h,w] * att[w,u] --------------------
// block per h. V rows for all c staged transposed+swizzled in 64KB LDS.
__global__ __launch_bounds__(256) void av_w_kernel(const float* __restrict__ dw,
        const float* __restrict__ att, float* __restrict__ out) {
    int h = blockIdx.x;
    __shared__ float Vt[16384];              // [w][c] swizzled
    int tid = threadIdx.x;
    const float* vb = dw + ((size_t)128 << 16) + h*256;
    for (int idx = tid; idx < 16384; idx += 256) {
        int c = idx >> 8, w = idx & 255;     // lanes vary w: coalesced global
        float val = vb[((size_t)c << 16) + w];
        Vt[w*64 + (((c >> 2) ^ (w & 15)) << 2) + (c & 3)] = val;
    }
    __syncthreads();
    float4 acc[16];
    #pragma unroll
    for (int k = 0; k < 16; ++k) acc[k] = make_float4(0.f, 0.f, 0.f, 0.f);
    const float* ap = att + tid;             // att[w][u=tid]
    const float4* Vt4 = (const float4*)Vt;
    for (int w = 0; w < 256; ++w) {
        float aw = ap[(size_t)w * 256];
        const float4* vr = Vt4 + w * 16;
        int sw = w & 15;
        #pragma unroll
        for (int k = 0; k < 16; ++k) {
            float4 vv = vr[k ^ sw];
            acc[k].x += vv.x*aw; acc[k].y += vv.y*aw; acc[k].z += vv.z*aw; acc[k].w += vv.w*aw;
        }
    }
    float* ob = out + h*256 + tid;
    #pragma unroll
    for (int k = 0; k < 16; ++k) {
        ob[(size_t)(4*k+0) * P_] = acc[k].x;
        ob[(size_t)(4*k+1) * P_] = acc[k].y;
        ob[(size_t)(4*k+2) * P_] = acc[k].z;
        ob[(size_t)(4*k+3) * P_] = acc[k].w;
    }
}

// ---------------- out[c,h,w] = sum_g att[h,g] * v[c,g,w] --------------------
// block per (h-tile of 64, c). att tile staged transposed+swizzled.
__global__ __launch_bounds__(256) void av_h_kernel(const float* __restrict__ dw,
        const float* __restrict__ att, float* __restrict__ out) {
    int ht = blockIdx.x, c = blockIdx.y;
    __shared__ float At[16384];              // [g][hh] swizzled
    int tid = threadIdx.x;
    const float* ab = att + (size_t)(ht*64) * 256;
    for (int idx = tid; idx < 16384; idx += 256) {
        int hh = idx >> 8, g = idx & 255;    // lanes vary g: coalesced global
        float val = ab[hh*256 + g];
        At[g*64 + (((hh >> 2) ^ (g & 15)) << 2) + (hh & 3)] = val;
    }
    __syncthreads();
    float4 acc[16];
    #pragma unroll
    for (int k = 0; k < 16; ++k) acc[k] = make_float4(0.f, 0.f, 0.f, 0.f);
    const float* vp = dw + ((size_t)(128 + c) << 16) + tid;
    const float4* At4 = (const float4*)At;
    for (int g = 0; g < 256; ++g) {
        float vg = vp[(size_t)g * 256];
        const float4* ar = At4 + g * 16;
        int sw = g & 15;
        #pragma unroll
        for (int k = 0; k < 16; ++k) {
            float4 vv = ar[k ^ sw];
            acc[k].x += vv.x*vg; acc[k].y += vv.y*vg; acc[k].z += vv.z*vg; acc[k].w += vv.w*vg;
        }
    }
    float* ob = out + ((size_t)c << 16) + ht*64*256 + tid;
    #pragma unroll
    for (int k = 0; k < 16; ++k) {
        ob[(4*k+0) * 256] = acc[k].x;
        ob[(4*k+1) * 256] = acc[k].y;
        ob[(4*k+2) * 256] = acc[k].z;
        ob[(4*k+3) * 256] = acc[k].w;
    }
}

// ---------------------------------------------------------------------------
extern "C" void kernel_launch(void* const* d_in, const int* in_sizes, int n_in,
                              void* d_out, int out_size, void* d_ws, size_t ws_size,
                              hipStream_t stream) {
    (void)in_sizes; (void)n_in; (void)out_size; (void)ws_size;
    const float* x = (const float*)d_in[0];
    float* ws  = (float*)d_ws;
    float* out = (float*)d_out;
    float* DW   = ws + DW_OFF;
    float* QKV  = ws + QKV_OFF;
    float* Y    = ws + Y_OFF;
    float* ATTP = ws + ATTP_OFF;
    float* ATT  = ws + ATT_OFF;
    float* HID  = ws + HID_OFF;
    float* Y2   = ws + Y2_OFF;
    float* G    = ws + G_OFF;

    for (int b = 0; b < 4; ++b) {
        const float* xb = x + (size_t)b * 64 * P_;
        float* outb = out + (size_t)b * 64 * P_;

        // ============ stage A: attention over W (wxw); m -> d_out ============
        ln_kernel<<<256, 256, 0, stream>>>(xb, (const float*)d_in[2], (const float*)d_in[3], Y);
        conv1x1_kernel<64><<<1024, 256, 64*64*4, stream>>>(Y, (const float*)d_in[4],
                (const float*)d_in[5], QKV, nullptr, 192);
        dwconv_kernel<<<49152, 256, 0, stream>>>(QKV, (const float*)d_in[6],
                (const float*)d_in[7], DW);
        l2norm_w_kernel<<<32768, 256, 0, stream>>>(DW);
        attn_gemm_kernel<false><<<dim3(16,4), 256, 0, stream>>>(DW, ATTP);
        softmax_kernel<<<256, 256, 0, stream>>>(ATTP, (const float*)d_in[10], ATT);
        av_w_kernel<<<256, 256, 0, stream>>>(DW, ATT, Y);
        conv1x1_kernel<64><<<1024, 256, 64*64*4, stream>>>(Y, (const float*)d_in[8],
                (const float*)d_in[9], outb, xb, 64);

        // ============ stage B: attention over H (hxh); z -> d_out ============
        ln_kernel<<<256, 256, 0, stream>>>(outb, (const float*)d_in[11], (const float*)d_in[12], Y);
        conv1x1_kernel<64><<<1024, 256, 64*64*4, stream>>>(Y, (const float*)d_in[13],
                (const float*)d_in[14], QKV, nullptr, 192);
        dwconv_kernel<<<49152, 256, 0, stream>>>(QKV, (const float*)d_in[15],
                (const float*)d_in[16], DW);
        l2norm_h_kernel<<<dim3(256,2), 256, 0, stream>>>(DW);
        attn_gemm_kernel<true><<<dim3(16,4), 256, 0, stream>>>(DW, ATTP);
        softmax_kernel<<<256, 256, 0, stream>>>(ATTP, (const float*)d_in[19], ATT);
        av_h_kernel<<<dim3(4,64), 256, 0, stream>>>(DW, ATT, Y);
        conv1x1_kernel<64><<<1024, 256, 64*64*4, stream>>>(Y, (const float*)d_in[17],
                (const float*)d_in[18], outb, outb, 64);   // in-place residual

        // ============ stage C: gated FFN; z + ffn -> d_out ============
        ln_kernel<<<256, 256, 0, stream>>>(outb, (const float*)d_in[20], (const float*)d_in[21], Y2);
        conv1x1_kernel<64><<<1024, 256, 64*64*4, stream>>>(Y2, (const float*)d_in[22],
                (const float*)d_in[23], HID, nullptr, 340);
        ffn_dw_kernel<<<43520, 256, 0, stream>>>(HID, (const float*)d_in[24],
                (const float*)d_in[25], G);
        conv1x1_kernel<170><<<1024, 256, 170*64*4, stream>>>(G, (const float*)d_in[26],
                (const float*)d_in[27], outb, outb, 64);   // in-place residual
    }
}

// Round 3
// 3166.599 us; speedup vs baseline: 1.5310x; 1.5310x over previous
//
#include <hip/hip_runtime.h>
#include <math.h>

// Problem constants (per batch): C=64, H=W=256, P=65536 pixels.
#define P_ 65536

// ---- per-batch workspace layout (float offsets). Peak = 33,423,360 floats
// ---- = 127.5 MiB (identical to round-2 known-good footprint).
#define DW_OFF   0ul            // 192*P (q,k,v post-dwconv)
#define QKV_OFF  12582912ul     // 192*P (pre-dwconv)
#define Y_OFF    25165824ul     // 64*P  (attn out)
#define ATTP_OFF 29360128ul     // 32*P  (K-split partials)
#define ATT_OFF  31457280ul     // P     (softmaxed attention)
// stage C overlays:
#define HID_OFF  0ul            // 340*P
#define G_OFF    22282240ul     // 170*P

// ---------------- fused [LN? ->] 1x1 conv [-> +residual?] -------------------
// 64-pixel tile + weights staged in LDS. Thread = (pixel-group of 4, o-group
// of 4). Inner: 8 ds_read_b128 : 64 FMA. Weight rows padded to 68 floats so
// the 4 og-groups of a wave hit staggered banks.
template<int COUT, bool LN, bool RES>
__global__ __launch_bounds__(256) void conv64_kernel(
        const float* __restrict__ in, const float* __restrict__ lnw,
        const float* __restrict__ lnb, const float* __restrict__ Wt,
        const float* __restrict__ bias, float* __restrict__ out,
        const float* __restrict__ res) {
    __shared__ float sIn[64*64];             // [c][p]
    __shared__ float sW[64*68];              // o-chunk [o][c] stride 68
    __shared__ float sMu[64], sInv[64], sPa[256], sPb[256];
    int tid = threadIdx.x;
    int hw0 = blockIdx.x * 64;
    {   // stage input, vectorized (1 KiB per wave-load)
        float4* sIn4 = (float4*)sIn;
        #pragma unroll
        for (int i4 = tid; i4 < 1024; i4 += 256) {
            int c = i4 >> 4, p4 = i4 & 15;
            sIn4[i4] = *(const float4*)(in + (size_t)c * P_ + hw0 + p4*4);
        }
    }
    __syncthreads();
    if constexpr (LN) {                      // per-pixel LN over 64 channels
        int p = tid & 63, q = tid >> 6;
        float s = 0.f, s2 = 0.f;
        #pragma unroll
        for (int c = q*16; c < q*16+16; ++c) {
            float v = sIn[c*64 + p]; s += v; s2 += v*v;
        }
        sPa[q*64+p] = s; sPb[q*64+p] = s2;
        __syncthreads();
        if (tid < 64) {
            float ss = sPa[tid]+sPa[64+tid]+sPa[128+tid]+sPa[192+tid];
            float qq = sPb[tid]+sPb[64+tid]+sPb[128+tid]+sPb[192+tid];
            float mu = ss * (1.f/64.f);
            float var = qq * (1.f/64.f) - mu*mu;
            sMu[tid] = mu; sInv[tid] = rsqrtf(var + 1e-5f);
        }
        __syncthreads();
        for (int idx = tid; idx < 4096; idx += 256) {
            int c = idx >> 6, p = idx & 63;
            sIn[idx] = (sIn[idx]-sMu[p])*sInv[p]*lnw[c] + lnb[c];
        }
    }
    int pg = tid & 15, og = tid >> 4;
    const float4* sIn4 = (const float4*)sIn;
    for (int o0 = 0; o0 < COUT; o0 += 64) {
        int rem = (COUT - o0 < 64) ? COUT - o0 : 64;
        __syncthreads();
        {   // stage weight chunk
            float4* sW4 = (float4*)sW;
            const float4* Wt4 = (const float4*)(Wt + (size_t)o0 * 64);
            for (int i4 = tid; i4 < rem*16; i4 += 256) {
                int o = i4 >> 4, c4 = i4 & 15;
                sW4[o*17 + c4] = Wt4[o*16 + c4];
            }
        }
        __syncthreads();
        if (og*4 < rem) {
            float4 acc[4];
            #pragma unroll
            for (int j = 0; j < 4; ++j) {
                float bv = bias[o0 + og*4 + j];
                acc[j] = make_float4(bv,bv,bv,bv);
            }
            #pragma unroll 4
            for (int c0 = 0; c0 < 64; c0 += 4) {
                float4 i0 = sIn4[(c0+0)*16 + pg];
                float4 i1 = sIn4[(c0+1)*16 + pg];
                float4 i2 = sIn4[(c0+2)*16 + pg];
                float4 i3 = sIn4[(c0+3)*16 + pg];
                #pragma unroll
                for (int j = 0; j < 4; ++j) {
                    float4 wv = *(const float4*)&sW[(og*4+j)*68 + c0];
                    acc[j].x += wv.x*i0.x + wv.y*i1.x + wv.z*i2.x + wv.w*i3.x;
                    acc[j].y += wv.x*i0.y + wv.y*i1.y + wv.z*i2.y + wv.w*i3.y;
                    acc[j].z += wv.x*i0.z + wv.y*i1.z + wv.z*i2.z + wv.w*i3.z;
                    acc[j].w += wv.x*i0.w + wv.y*i1.w + wv.z*i2.w + wv.w*i3.w;
                }
            }
            #pragma unroll
            for (int j = 0; j < 4; ++j) {
                size_t ob = (size_t)(o0 + og*4 + j) * P_ + hw0 + pg*4;
                float4 r = acc[j];
                if constexpr (RES) {
                    float4 rv = *(const float4*)(res + ob);
                    r.x += rv.x; r.y += rv.y; r.z += rv.z; r.w += rv.w;
                }
                *(float4*)(out + ob) = r;
            }
        }
    }
}

// -------- 1x1 conv CIN=170 -> 64 with residual (FFN output projection) -----
// K chunked 88+88 (zero-padded past 170); weights [64][92-pad] in LDS.
__global__ __launch_bounds__(256) void conv170_kernel(
        const float* __restrict__ in, const float* __restrict__ Wt,
        const float* __restrict__ bias, float* __restrict__ out,
        const float* __restrict__ res) {
    __shared__ float sIn[88*64];
    __shared__ float sW[64*92];
    int tid = threadIdx.x;
    int hw0 = blockIdx.x * 64;
    int pg = tid & 15, og = tid >> 4;
    float4 acc[4];
    #pragma unroll
    for (int j = 0; j < 4; ++j) {
        float bv = bias[og*4 + j];
        acc[j] = make_float4(bv,bv,bv,bv);
    }
    for (int cc0 = 0; cc0 < 176; cc0 += 88) {
        __syncthreads();
        {   float4* sIn4 = (float4*)sIn;
            for (int i4 = tid; i4 < 88*16; i4 += 256) {
                int cl = i4 >> 4, p4 = i4 & 15;
                int c = cc0 + cl;
                sIn4[i4] = (c < 170)
                    ? *(const float4*)(in + (size_t)c * P_ + hw0 + p4*4)
                    : make_float4(0.f,0.f,0.f,0.f);
            }
        }
        for (int idx = tid; idx < 64*88; idx += 256) {
            int o = idx / 88, cl = idx - o*88;
            int c = cc0 + cl;
            sW[o*92 + cl] = (c < 170) ? Wt[(size_t)o*170 + c] : 0.f;
        }
        __syncthreads();
        const float4* sIn4 = (const float4*)sIn;
        #pragma unroll 2
        for (int c0 = 0; c0 < 88; c0 += 4) {
            float4 i0 = sIn4[(c0+0)*16 + pg];
            float4 i1 = sIn4[(c0+1)*16 + pg];
            float4 i2 = sIn4[(c0+2)*16 + pg];
            float4 i3 = sIn4[(c0+3)*16 + pg];
            #pragma unroll
            for (int j = 0; j < 4; ++j) {
                float4 wv = *(const float4*)&sW[(og*4+j)*92 + c0];
                acc[j].x += wv.x*i0.x + wv.y*i1.x + wv.z*i2.x + wv.w*i3.x;
                acc[j].y += wv.x*i0.y + wv.y*i1.y + wv.z*i2.y + wv.w*i3.y;
                acc[j].z += wv.x*i0.z + wv.y*i1.z + wv.z*i2.z + wv.w*i3.z;
                acc[j].w += wv.x*i0.w + wv.y*i1.w + wv.z*i2.w + wv.w*i3.w;
            }
        }
    }
    #pragma unroll
    for (int j = 0; j < 4; ++j) {
        size_t ob = (size_t)(og*4 + j) * P_ + hw0 + pg*4;
        float4 rv = *(const float4*)(res + ob);
        float4 r = acc[j];
        r.x += rv.x; r.y += rv.y; r.z += rv.z; r.w += rv.w;
        *(float4*)(out + ob) = r;
    }
}

// ------- depthwise 3x3 + bias, fused l2norm over w for channels < 128 ------
// block = one (channel, h) row of 256 outputs.
__global__ __launch_bounds__(256) void dwrow_norm_kernel(const float* __restrict__ in,
        const float* __restrict__ w9, const float* __restrict__ bias,
        float* __restrict__ out) {
    int h = blockIdx.x, o = blockIdx.y;
    int w = threadIdx.x;
    const float* ip = in + ((size_t)o << 16);
    const float* wp = w9 + o * 9;
    float acc = bias[o];
    #pragma unroll
    for (int dy = -1; dy <= 1; ++dy) {
        int hh = h + dy;
        if (hh < 0 || hh > 255) continue;
        const float* row = ip + hh*256;
        #pragma unroll
        for (int dx = -1; dx <= 1; ++dx) {
            int ww = w + dx;
            if (ww < 0 || ww > 255) continue;
            acc += wp[(dy+1)*3 + (dx+1)] * row[ww];
        }
    }
    if (o < 128) {                           // q,k rows: l2-normalize over w
        float s = acc * acc;
        #pragma unroll
        for (int off = 32; off; off >>= 1) s += __shfl_down(s, off, 64);
        __shared__ float red[4];
        int wv = w >> 6, ln = w & 63;
        if (ln == 0) red[wv] = s;
        __syncthreads();
        float tot = red[0] + red[1] + red[2] + red[3];
        acc *= 1.0f / fmaxf(sqrtf(tot), 1e-12f);
    }
    out[((size_t)o << 16) + h*256 + w] = acc;
}

// ---------------- plain depthwise 3x3 + bias (stage B) ----------------------
__global__ __launch_bounds__(256) void dwconv_kernel(const float* __restrict__ in,
        const float* __restrict__ w9, const float* __restrict__ bias,
        float* __restrict__ out) {
    size_t t = (size_t)blockIdx.x * 256 + threadIdx.x;
    int hw = (int)(t & 65535);
    int o = (int)(t >> 16);
    int h = hw >> 8, w = hw & 255;
    const float* ip = in + ((size_t)o << 16);
    const float* wp = w9 + o * 9;
    float acc = bias[o];
    #pragma unroll
    for (int dy = -1; dy <= 1; ++dy) {
        int hh = h + dy;
        if (hh < 0 || hh > 255) continue;
        #pragma unroll
        for (int dx = -1; dx <= 1; ++dx) {
            int ww = w + dx;
            if (ww < 0 || ww > 255) continue;
            acc += wp[(dy+1)*3 + (dx+1)] * ip[hh*256 + ww];
        }
    }
    out[t] = acc;
}

// ---------------- FFN depthwise 3x3 fused with exact-GELU gate --------------
__global__ __launch_bounds__(256) void ffn_dw_kernel(const float* __restrict__ hid,
        const float* __restrict__ w9, const float* __restrict__ bias,
        float* __restrict__ g) {
    size_t t = (size_t)blockIdx.x * 256 + threadIdx.x;   // 170*P_ threads
    int hw = (int)(t & 65535);
    int i = (int)(t >> 16);
    int h = hw >> 8, w = hw & 255;
    const float* ip1 = hid + ((size_t)i << 16);
    const float* ip2 = ip1 + ((size_t)170 << 16);
    const float* wp1 = w9 + i * 9;
    const float* wp2 = w9 + (i + 170) * 9;
    float a = bias[i], b2 = bias[i + 170];
    #pragma unroll
    for (int dy = -1; dy <= 1; ++dy) {
        int hh = h + dy;
        if (hh < 0 || hh > 255) continue;
        #pragma unroll
        for (int dx = -1; dx <= 1; ++dx) {
            int ww = w + dx;
            if (ww < 0 || ww > 255) continue;
            int off = hh*256 + ww;
            int ki = (dy+1)*3 + (dx+1);
            a  += wp1[ki] * ip1[off];
            b2 += wp2[ki] * ip2[off];
        }
    }
    float ge = 0.5f * a * (1.0f + erff(a * 0.70710678118654752440f));
    g[t] = ge * b2;
}

// ---------------- l2 normalize over (c,w), per (q|k, h) ---------------------
__global__ __launch_bounds__(256) void l2norm_h_kernel(float* __restrict__ dw) {
    int h = blockIdx.x, qk = blockIdx.y;
    float* base = dw + ((size_t)(qk*64) << 16) + h*256;
    int tid = threadIdx.x;
    float s = 0.f;
    for (int idx = tid; idx < 16384; idx += 256) {
        int c = idx >> 8, w = idx & 255;
        float v = base[((size_t)c << 16) + w];
        s += v * v;
    }
    #pragma unroll
    for (int off = 32; off; off >>= 1) s += __shfl_down(s, off, 64);
    __shared__ float red[4];
    int wv = tid >> 6, ln = tid & 63;
    if (ln == 0) red[wv] = s;
    __syncthreads();
    float tot = red[0] + red[1] + red[2] + red[3];
    float inv = 1.0f / fmaxf(sqrtf(tot), 1e-12f);
    for (int idx = tid; idx < 16384; idx += 256) {
        int c = idx >> 8, w = idx & 255;
        base[((size_t)c << 16) + w] *= inv;
    }
}

// ---------------- attention logits GEMM, 32-way K-split over channels -------
// grid = (16 tiles, 32 ksplit); each block: 64x64 tile, K = 2 channels x 256.
template<bool RCONTIG>
__global__ __launch_bounds__(256) void attn_gemm_kernel(const float* __restrict__ dw,
        float* __restrict__ part) {
    int tile = blockIdx.x, ks = blockIdx.y;
    int i0 = (tile & 3) * 64, j0 = (tile >> 2) * 64;
    const float* qb = dw;
    const float* kb = dw + ((size_t)64 << 16);
    __shared__ float Qt[16 * 68];
    __shared__ float Kt[16 * 68];
    int tid = threadIdx.x;
    int tx = tid & 15, ty = tid >> 4;
    float acc[4][4] = {{0.f}};
    for (int c = ks * 2; c < ks * 2 + 2; ++c) {
        const float* qc = qb + ((size_t)c << 16);
        const float* kc = kb + ((size_t)c << 16);
        for (int r0 = 0; r0 < 256; r0 += 16) {
            __syncthreads();
            #pragma unroll
            for (int rep = 0; rep < 4; ++rep) {
                int idx = tid + rep * 256;
                if (RCONTIG) {
                    int rr = idx & 15, ii = idx >> 4;
                    Qt[rr*68 + ii] = qc[(i0+ii)*256 + r0+rr];
                    Kt[rr*68 + ii] = kc[(j0+ii)*256 + r0+rr];
                } else {
                    int ii = idx & 63, rr = idx >> 6;
                    Qt[rr*68 + ii] = qc[(r0+rr)*256 + i0+ii];
                    Kt[rr*68 + ii] = kc[(r0+rr)*256 + j0+ii];
                }
            }
            __syncthreads();
            #pragma unroll
            for (int rr = 0; rr < 16; ++rr) {
                float4 qv = *(const float4*)&Qt[rr*68 + tx*4];
                float4 kv = *(const float4*)&Kt[rr*68 + ty*4];
                acc[0][0] += qv.x*kv.x; acc[0][1] += qv.x*kv.y; acc[0][2] += qv.x*kv.z; acc[0][3] += qv.x*kv.w;
                acc[1][0] += qv.y*kv.x; acc[1][1] += qv.y*kv.y; acc[1][2] += qv.y*kv.z; acc[1][3] += qv.y*kv.w;
                acc[2][0] += qv.z*kv.x; acc[2][1] += qv.z*kv.y; acc[2][2] += qv.z*kv.z; acc[2][3] += qv.z*kv.w;
                acc[3][0] += qv.w*kv.x; acc[3][1] += qv.w*kv.y; acc[3][2] += qv.w*kv.z; acc[3][3] += qv.w*kv.w;
            }
        }
    }
    size_t pb = (size_t)ks * 65536;
    #pragma unroll
    for (int a = 0; a < 4; ++a)
        #pragma unroll
        for (int b2 = 0; b2 < 4; ++b2)
            part[pb + (size_t)(i0 + tx*4 + a) * 256 + (j0 + ty*4 + b2)] = acc[a][b2];
}

// ---------------- sum 32 K-split partials, scale by temp, softmax row -------
__global__ __launch_bounds__(256) void softmax_kernel(const float* __restrict__ part,
        const float* __restrict__ temp, float* __restrict__ att) {
    int i = blockIdx.x;
    int j = threadIdx.x;
    size_t rowoff = (size_t)i * 256 + j;
    float s = 0.f;
    #pragma unroll
    for (int kk = 0; kk < 32; ++kk) s += part[(size_t)kk * 65536 + rowoff];
    s *= temp[0];
    __shared__ float redA[4], redB[4];
    int wv = j >> 6, ln = j & 63;
    float m = s;
    #pragma unroll
    for (int off = 32; off; off >>= 1) m = fmaxf(m, __shfl_down(m, off, 64));
    if (ln == 0) redA[wv] = m;
    __syncthreads();
    m = fmaxf(fmaxf(redA[0], redA[1]), fmaxf(redA[2], redA[3]));
    float e = expf(s - m);
    float t2 = e;
    #pragma unroll
    for (int off = 32; off; off >>= 1) t2 += __shfl_down(t2, off, 64);
    if (ln == 0) redB[wv] = t2;
    __syncthreads();
    float tot = redB[0] + redB[1] + redB[2] + redB[3];
    att[rowoff] = e / tot;
}

// ---------------- out[c,h,u] = sum_w v[c,h,w] * att[w,u] --------------------
__global__ __launch_bounds__(256) void av_w_kernel(const float* __restrict__ dw,
        const float* __restrict__ att, float* __restrict__ out) {
    int h = blockIdx.x;
    __shared__ float Vt[16384];              // [w][c] swizzled
    int tid = threadIdx.x;
    const float* vb = dw + ((size_t)128 << 16) + h*256;
    for (int idx = tid; idx < 16384; idx += 256) {
        int c = idx >> 8, w = idx & 255;
        float val = vb[((size_t)c << 16) + w];
        Vt[w*64 + (((c >> 2) ^ (w & 15)) << 2) + (c & 3)] = val;
    }
    __syncthreads();
    float4 acc[16];
    #pragma unroll
    for (int k = 0; k < 16; ++k) acc[k] = make_float4(0.f, 0.f, 0.f, 0.f);
    const float* ap = att + tid;
    const float4* Vt4 = (const float4*)Vt;
    for (int w = 0; w < 256; ++w) {
        float aw = ap[(size_t)w * 256];
        const float4* vr = Vt4 + w * 16;
        int sw = w & 15;
        #pragma unroll
        for (int k = 0; k < 16; ++k) {
            float4 vv = vr[k ^ sw];
            acc[k].x += vv.x*aw; acc[k].y += vv.y*aw; acc[k].z += vv.z*aw; acc[k].w += vv.w*aw;
        }
    }
    float* ob = out + h*256 + tid;
    #pragma unroll
    for (int k = 0; k < 16; ++k) {
        ob[(size_t)(4*k+0) * P_] = acc[k].x;
        ob[(size_t)(4*k+1) * P_] = acc[k].y;
        ob[(size_t)(4*k+2) * P_] = acc[k].z;
        ob[(size_t)(4*k+3) * P_] = acc[k].w;
    }
}

// ---------------- out[c,h,w] = sum_g att[h,g] * v[c,g,w] --------------------
__global__ __launch_bounds__(256) void av_h_kernel(const float* __restrict__ dw,
        const float* __restrict__ att, float* __restrict__ out) {
    int ht = blockIdx.x, c = blockIdx.y;
    __shared__ float At[16384];              // [g][hh] swizzled
    int tid = threadIdx.x;
    const float* ab = att + (size_t)(ht*64) * 256;
    for (int idx = tid; idx < 16384; idx += 256) {
        int hh = idx >> 8, g = idx & 255;
        float val = ab[hh*256 + g];
        At[g*64 + (((hh >> 2) ^ (g & 15)) << 2) + (hh & 3)] = val;
    }
    __syncthreads();
    float4 acc[16];
    #pragma unroll
    for (int k = 0; k < 16; ++k) acc[k] = make_float4(0.f, 0.f, 0.f, 0.f);
    const float* vp = dw + ((size_t)(128 + c) << 16) + tid;
    const float4* At4 = (const float4*)At;
    for (int g = 0; g < 256; ++g) {
        float vg = vp[(size_t)g * 256];
        const float4* ar = At4 + g * 16;
        int sw = g & 15;
        #pragma unroll
        for (int k = 0; k < 16; ++k) {
            float4 vv = ar[k ^ sw];
            acc[k].x += vv.x*vg; acc[k].y += vv.y*vg; acc[k].z += vv.z*vg; acc[k].w += vv.w*vg;
        }
    }
    float* ob = out + ((size_t)c << 16) + ht*64*256 + tid;
    #pragma unroll
    for (int k = 0; k < 16; ++k) {
        ob[(4*k+0) * 256] = acc[k].x;
        ob[(4*k+1) * 256] = acc[k].y;
        ob[(4*k+2) * 256] = acc[k].z;
        ob[(4*k+3) * 256] = acc[k].w;
    }
}

// ---------------------------------------------------------------------------
extern "C" void kernel_launch(void* const* d_in, const int* in_sizes, int n_in,
                              void* d_out, int out_size, void* d_ws, size_t ws_size,
                              hipStream_t stream) {
    (void)in_sizes; (void)n_in; (void)out_size; (void)ws_size;
    const float* x = (const float*)d_in[0];
    float* ws  = (float*)d_ws;
    float* out = (float*)d_out;
    float* DW   = ws + DW_OFF;
    float* QKV  = ws + QKV_OFF;
    float* Y    = ws + Y_OFF;
    float* ATTP = ws + ATTP_OFF;
    float* ATT  = ws + ATT_OFF;
    float* HID  = ws + HID_OFF;
    float* G    = ws + G_OFF;

    for (int b = 0; b < 4; ++b) {
        const float* xb = x + (size_t)b * 64 * P_;
        float* outb = out + (size_t)b * 64 * P_;

        // ===== stage A: attention over W (wxw); m -> d_out =====
        conv64_kernel<192,true,false><<<1024, 256, 0, stream>>>(xb,
                (const float*)d_in[2], (const float*)d_in[3],
                (const float*)d_in[4], (const float*)d_in[5], QKV, nullptr);
        dwrow_norm_kernel<<<dim3(256,192), 256, 0, stream>>>(QKV,
                (const float*)d_in[6], (const float*)d_in[7], DW);
        attn_gemm_kernel<false><<<dim3(16,32), 256, 0, stream>>>(DW, ATTP);
        softmax_kernel<<<256, 256, 0, stream>>>(ATTP, (const float*)d_in[10], ATT);
        av_w_kernel<<<256, 256, 0, stream>>>(DW, ATT, Y);
        conv64_kernel<64,false,true><<<1024, 256, 0, stream>>>(Y,
                nullptr, nullptr,
                (const float*)d_in[8], (const float*)d_in[9], outb, xb);

        // ===== stage B: attention over H (hxh); z -> d_out =====
        conv64_kernel<192,true,false><<<1024, 256, 0, stream>>>(outb,
                (const float*)d_in[11], (const float*)d_in[12],
                (const float*)d_in[13], (const float*)d_in[14], QKV, nullptr);
        dwconv_kernel<<<49152, 256, 0, stream>>>(QKV, (const float*)d_in[15],
                (const float*)d_in[16], DW);
        l2norm_h_kernel<<<dim3(256,2), 256, 0, stream>>>(DW);
        attn_gemm_kernel<true><<<dim3(16,32), 256, 0, stream>>>(DW, ATTP);
        softmax_kernel<<<256, 256, 0, stream>>>(ATTP, (const float*)d_in[19], ATT);
        av_h_kernel<<<dim3(4,64), 256, 0, stream>>>(DW, ATT, Y);
        conv64_kernel<64,false,true><<<1024, 256, 0, stream>>>(Y,
                nullptr, nullptr,
                (const float*)d_in[17], (const float*)d_in[18], outb, outb);

        // ===== stage C: gated FFN; z + ffn -> d_out =====
        conv64_kernel<340,true,false><<<1024, 256, 0, stream>>>(outb,
                (const float*)d_in[20], (const float*)d_in[21],
                (const float*)d_in[22], (const float*)d_in[23], HID, nullptr);
        ffn_dw_kernel<<<43520, 256, 0, stream>>>(HID, (const float*)d_in[24],
                (const float*)d_in[25], G);
        conv170_kernel<<<1024, 256, 0, stream>>>(G, (const float*)d_in[26],
                (const float*)d_in[27], outb, outb);
    }
}

// Round 4
// 2867.053 us; speedup vs baseline: 1.6909x; 1.1045x over previous
//
#include <hip/hip_runtime.h>
#include <math.h>

// Problem constants (per batch): C=64, H=W=256, P=65536 pixels.
#define P_ 65536

// ---- per-batch workspace layout (float offsets). Peak = 33,423,360 floats
// ---- = 127.5 MiB (identical to round-2/3 known-good footprint).
#define DW_OFF   0ul            // 192*P (q,k,v post-dwconv)
#define QKV_OFF  12582912ul     // 192*P (pre-dwconv)  [dead after dwconv]
#define ATTP_OFF QKV_OFF        // 64*P K-split partials ALIAS dead QKV region
#define Y_OFF    25165824ul     // 64*P  (attn out)
#define ATT_OFF  31457280ul     // P     (softmaxed attention)
// stage C overlays:
#define HID_OFF  0ul            // 340*P
#define G_OFF    22282240ul     // 170*P

// ============ unified 128x128-tile GEMM core, 8x8 micro-tile ================
// 256 threads: tx=tid&15 (N-frag of 8), ty=tid>>4 (M-frag of 8). K chunks of
// 16 staged in LDS rows padded to 132 floats. Inner: 4 ds_read_b128 : 64 FMA.
#define GEMM_ACC_DECL float4 acc[8][2]; \
    _Pragma("unroll") for (int a_ = 0; a_ < 8; ++a_) { \
        acc[a_][0] = make_float4(0.f,0.f,0.f,0.f); \
        acc[a_][1] = make_float4(0.f,0.f,0.f,0.f); }

__device__ __forceinline__ void gemm_inner16(const float* As, const float* Bs,
        int tx, int ty, float4 acc[8][2]) {
    const float4* As4 = (const float4*)As;
    const float4* Bs4 = (const float4*)Bs;
    #pragma unroll
    for (int kk = 0; kk < 16; ++kk) {
        float4 a0 = As4[kk*33 + ty*2];
        float4 a1 = As4[kk*33 + ty*2 + 1];
        float4 b0 = Bs4[kk*33 + tx*2];
        float4 b1 = Bs4[kk*33 + tx*2 + 1];
        float av[8] = {a0.x,a0.y,a0.z,a0.w,a1.x,a1.y,a1.z,a1.w};
        #pragma unroll
        for (int a = 0; a < 8; ++a) {
            acc[a][0].x += av[a]*b0.x; acc[a][0].y += av[a]*b0.y;
            acc[a][0].z += av[a]*b0.z; acc[a][0].w += av[a]*b0.w;
            acc[a][1].x += av[a]*b1.x; acc[a][1].y += av[a]*b1.y;
            acc[a][1].z += av[a]*b1.z; acc[a][1].w += av[a]*b1.w;
        }
    }
}

// ---- attention logits: part[ks][i][j] = sum_r Q[ks][r-dims][i]*K[ks][...][j]
// RCONTIG=false (stage A): A[i,r] = q[c=ks, h=r, w=i] (i contiguous in mem)
// RCONTIG=true  (stage B): A[i,r] = q[c=ks, h=i, w=r] (r contiguous in mem)
template<bool RCONTIG>
__global__ __launch_bounds__(256) void attn_gemm_kernel(const float* __restrict__ dw,
        float* __restrict__ part) {
    __shared__ float As[16*132], Bs[16*132];
    int tid = threadIdx.x, tx = tid & 15, ty = tid >> 4;
    int i0 = (blockIdx.x & 1) * 128, j0 = (blockIdx.x >> 1) * 128;
    int ks = blockIdx.y;                       // channel
    const float* qc = dw + ((size_t)ks << 16);
    const float* kc = dw + ((size_t)(64 + ks) << 16);
    GEMM_ACC_DECL
    for (int r0 = 0; r0 < 256; r0 += 16) {
        __syncthreads();
        #pragma unroll
        for (int rep = 0; rep < 8; ++rep) {
            int idx = tid + rep * 256;
            if (RCONTIG) {
                int ii = idx >> 4, rr = idx & 15;
                As[rr*132 + ii] = qc[(i0+ii)*256 + r0+rr];
                Bs[rr*132 + ii] = kc[(j0+ii)*256 + r0+rr];
            } else {
                int rr = idx >> 7, ii = idx & 127;
                As[rr*132 + ii] = qc[(r0+rr)*256 + i0+ii];
                Bs[rr*132 + ii] = kc[(r0+rr)*256 + j0+ii];
            }
        }
        __syncthreads();
        gemm_inner16(As, Bs, tx, ty, acc);
    }
    float* pb = part + (size_t)ks * 65536;
    #pragma unroll
    for (int a = 0; a < 8; ++a) {
        float* row = pb + (size_t)(i0 + ty*8 + a) * 256 + j0 + tx*8;
        *(float4*)row = acc[a][0];
        *(float4*)(row + 4) = acc[a][1];
    }
}

// ---- av_w as GEMM: Out[(h,c), u] = sum_w V[c,h,w] * Att[w,u]; M=16384 ------
__global__ __launch_bounds__(256) void av_w_kernel(const float* __restrict__ dw,
        const float* __restrict__ att, float* __restrict__ out) {
    __shared__ float As[16*132], Bs[16*132];
    int tid = threadIdx.x, tx = tid & 15, ty = tid >> 4;
    int m0 = blockIdx.x * 128;                 // m = h*64 + c
    int u0 = blockIdx.y * 128;
    GEMM_ACC_DECL
    for (int w0 = 0; w0 < 256; w0 += 16) {
        __syncthreads();
        #pragma unroll
        for (int rep = 0; rep < 8; ++rep) {
            int idx = tid + rep * 256;
            {   // A (V side): lanes vary wl (16 contiguous)
                int mm = idx >> 4, wl = idx & 15;
                int m = m0 + mm, c = m & 63, h = m >> 6;
                As[wl*132 + mm] = dw[((size_t)(128+c) << 16) + h*256 + w0+wl];
            }
            {   // B (att side): lanes vary uu (contiguous)
                int wl = idx >> 7, uu = idx & 127;
                Bs[wl*132 + uu] = att[(w0+wl)*256 + u0+uu];
            }
        }
        __syncthreads();
        gemm_inner16(As, Bs, tx, ty, acc);
    }
    #pragma unroll
    for (int a = 0; a < 8; ++a) {
        int m = m0 + ty*8 + a, c = m & 63, h = m >> 6;
        float* row = out + ((size_t)c << 16) + h*256 + u0 + tx*8;
        *(float4*)row = acc[a][0];
        *(float4*)(row + 4) = acc[a][1];
    }
}

// ---- av_h as GEMM: Out[(c,w), h] = sum_g V[c,g,w] * Att[h,g] ---------------
// A (ty side) = Att[h,g]; B (tx side) = V[(c,w), g]. bx: c = bx>>1, w-half.
__global__ __launch_bounds__(256) void av_h_kernel(const float* __restrict__ dw,
        const float* __restrict__ att, float* __restrict__ out) {
    __shared__ float As[16*132], Bs[16*132];
    int tid = threadIdx.x, tx = tid & 15, ty = tid >> 4;
    int c = blockIdx.x >> 1;
    int w0 = (blockIdx.x & 1) * 128;
    int h0 = blockIdx.y * 128;
    const float* vc = dw + ((size_t)(128 + c) << 16);
    GEMM_ACC_DECL
    for (int g0 = 0; g0 < 256; g0 += 16) {
        __syncthreads();
        #pragma unroll
        for (int rep = 0; rep < 8; ++rep) {
            int idx = tid + rep * 256;
            {   // A (att side): lanes vary gl (16 contiguous in att row)
                int hh = idx >> 4, gl = idx & 15;
                As[gl*132 + hh] = att[(h0+hh)*256 + g0+gl];
            }
            {   // B (V side): lanes vary mm (contiguous in w)
                int gl = idx >> 7, mm = idx & 127;
                Bs[gl*132 + mm] = vc[(g0+gl)*256 + w0+mm];
            }
        }
        __syncthreads();
        gemm_inner16(As, Bs, tx, ty, acc);
    }
    #pragma unroll
    for (int a = 0; a < 8; ++a) {
        int h = h0 + ty*8 + a;
        float* row = out + ((size_t)c << 16) + h*256 + w0 + tx*8;
        *(float4*)row = acc[a][0];
        *(float4*)(row + 4) = acc[a][1];
    }
}

// ---------------- sum 64 K-split partials, scale by temp, softmax row -------
__global__ __launch_bounds__(256) void softmax_kernel(const float* __restrict__ part,
        const float* __restrict__ temp, float* __restrict__ att) {
    int i = blockIdx.x;
    int j = threadIdx.x;
    size_t rowoff = (size_t)i * 256 + j;
    float s = 0.f;
    #pragma unroll
    for (int kk = 0; kk < 64; ++kk) s += part[(size_t)kk * 65536 + rowoff];
    s *= temp[0];
    __shared__ float redA[4], redB[4];
    int wv = j >> 6, ln = j & 63;
    float m = s;
    #pragma unroll
    for (int off = 32; off; off >>= 1) m = fmaxf(m, __shfl_down(m, off, 64));
    if (ln == 0) redA[wv] = m;
    __syncthreads();
    m = fmaxf(fmaxf(redA[0], redA[1]), fmaxf(redA[2], redA[3]));
    float e = expf(s - m);
    float t2 = e;
    #pragma unroll
    for (int off = 32; off; off >>= 1) t2 += __shfl_down(t2, off, 64);
    if (ln == 0) redB[wv] = t2;
    __syncthreads();
    float tot = redB[0] + redB[1] + redB[2] + redB[3];
    att[rowoff] = e / tot;
}

// ---------------- fused [LN? ->] 1x1 conv [-> +residual?] -------------------
template<int COUT, bool LN, bool RES>
__global__ __launch_bounds__(256) void conv64_kernel(
        const float* __restrict__ in, const float* __restrict__ lnw,
        const float* __restrict__ lnb, const float* __restrict__ Wt,
        const float* __restrict__ bias, float* __restrict__ out,
        const float* __restrict__ res) {
    __shared__ float sIn[64*64];             // [c][p]
    __shared__ float sW[64*68];              // o-chunk [o][c] stride 68
    __shared__ float sMu[64], sInv[64], sPa[256], sPb[256];
    int tid = threadIdx.x;
    int hw0 = blockIdx.x * 64;
    {   float4* sIn4 = (float4*)sIn;
        #pragma unroll
        for (int i4 = tid; i4 < 1024; i4 += 256) {
            int c = i4 >> 4, p4 = i4 & 15;
            sIn4[i4] = *(const float4*)(in + (size_t)c * P_ + hw0 + p4*4);
        }
    }
    __syncthreads();
    if constexpr (LN) {
        int p = tid & 63, q = tid >> 6;
        float s = 0.f, s2 = 0.f;
        #pragma unroll
        for (int c = q*16; c < q*16+16; ++c) {
            float v = sIn[c*64 + p]; s += v; s2 += v*v;
        }
        sPa[q*64+p] = s; sPb[q*64+p] = s2;
        __syncthreads();
        if (tid < 64) {
            float ss = sPa[tid]+sPa[64+tid]+sPa[128+tid]+sPa[192+tid];
            float qq = sPb[tid]+sPb[64+tid]+sPb[128+tid]+sPb[192+tid];
            float mu = ss * (1.f/64.f);
            float var = qq * (1.f/64.f) - mu*mu;
            sMu[tid] = mu; sInv[tid] = rsqrtf(var + 1e-5f);
        }
        __syncthreads();
        for (int idx = tid; idx < 4096; idx += 256) {
            int c = idx >> 6, p = idx & 63;
            sIn[idx] = (sIn[idx]-sMu[p])*sInv[p]*lnw[c] + lnb[c];
        }
    }
    int pg = tid & 15, og = tid >> 4;
    const float4* sIn4 = (const float4*)sIn;
    for (int o0 = 0; o0 < COUT; o0 += 64) {
        int rem = (COUT - o0 < 64) ? COUT - o0 : 64;
        __syncthreads();
        {   float4* sW4 = (float4*)sW;
            const float4* Wt4 = (const float4*)(Wt + (size_t)o0 * 64);
            for (int i4 = tid; i4 < rem*16; i4 += 256) {
                int o = i4 >> 4, c4 = i4 & 15;
                sW4[o*17 + c4] = Wt4[o*16 + c4];
            }
        }
        __syncthreads();
        if (og*4 < rem) {
            float4 acc[4];
            #pragma unroll
            for (int j = 0; j < 4; ++j) {
                float bv = bias[o0 + og*4 + j];
                acc[j] = make_float4(bv,bv,bv,bv);
            }
            #pragma unroll 4
            for (int c0 = 0; c0 < 64; c0 += 4) {
                float4 i0 = sIn4[(c0+0)*16 + pg];
                float4 i1 = sIn4[(c0+1)*16 + pg];
                float4 i2 = sIn4[(c0+2)*16 + pg];
                float4 i3 = sIn4[(c0+3)*16 + pg];
                #pragma unroll
                for (int j = 0; j < 4; ++j) {
                    float4 wv = *(const float4*)&sW[(og*4+j)*68 + c0];
                    acc[j].x += wv.x*i0.x + wv.y*i1.x + wv.z*i2.x + wv.w*i3.x;
                    acc[j].y += wv.x*i0.y + wv.y*i1.y + wv.z*i2.y + wv.w*i3.y;
                    acc[j].z += wv.x*i0.z + wv.y*i1.z + wv.z*i2.z + wv.w*i3.z;
                    acc[j].w += wv.x*i0.w + wv.y*i1.w + wv.z*i2.w + wv.w*i3.w;
                }
            }
            #pragma unroll
            for (int j = 0; j < 4; ++j) {
                size_t ob = (size_t)(o0 + og*4 + j) * P_ + hw0 + pg*4;
                float4 r = acc[j];
                if constexpr (RES) {
                    float4 rv = *(const float4*)(res + ob);
                    r.x += rv.x; r.y += rv.y; r.z += rv.z; r.w += rv.w;
                }
                *(float4*)(out + ob) = r;
            }
        }
    }
}

// -------- 1x1 conv CIN=170 -> 64 with residual (FFN output projection) -----
__global__ __launch_bounds__(256) void conv170_kernel(
        const float* __restrict__ in, const float* __restrict__ Wt,
        const float* __restrict__ bias, float* __restrict__ out,
        const float* __restrict__ res) {
    __shared__ float sIn[88*64];
    __shared__ float sW[64*92];
    int tid = threadIdx.x;
    int hw0 = blockIdx.x * 64;
    int pg = tid & 15, og = tid >> 4;
    float4 acc[4];
    #pragma unroll
    for (int j = 0; j < 4; ++j) {
        float bv = bias[og*4 + j];
        acc[j] = make_float4(bv,bv,bv,bv);
    }
    for (int cc0 = 0; cc0 < 176; cc0 += 88) {
        __syncthreads();
        {   float4* sIn4 = (float4*)sIn;
            for (int i4 = tid; i4 < 88*16; i4 += 256) {
                int cl = i4 >> 4, p4 = i4 & 15;
                int c = cc0 + cl;
                sIn4[i4] = (c < 170)
                    ? *(const float4*)(in + (size_t)c * P_ + hw0 + p4*4)
                    : make_float4(0.f,0.f,0.f,0.f);
            }
        }
        for (int idx = tid; idx < 64*88; idx += 256) {
            int o = idx / 88, cl = idx - o*88;
            int c = cc0 + cl;
            sW[o*92 + cl] = (c < 170) ? Wt[(size_t)o*170 + c] : 0.f;
        }
        __syncthreads();
        const float4* sIn4 = (const float4*)sIn;
        #pragma unroll 2
        for (int c0 = 0; c0 < 88; c0 += 4) {
            float4 i0 = sIn4[(c0+0)*16 + pg];
            float4 i1 = sIn4[(c0+1)*16 + pg];
            float4 i2 = sIn4[(c0+2)*16 + pg];
            float4 i3 = sIn4[(c0+3)*16 + pg];
            #pragma unroll
            for (int j = 0; j < 4; ++j) {
                float4 wv = *(const float4*)&sW[(og*4+j)*92 + c0];
                acc[j].x += wv.x*i0.x + wv.y*i1.x + wv.z*i2.x + wv.w*i3.x;
                acc[j].y += wv.x*i0.y + wv.y*i1.y + wv.z*i2.y + wv.w*i3.y;
                acc[j].z += wv.x*i0.z + wv.y*i1.z + wv.z*i2.z + wv.w*i3.z;
                acc[j].w += wv.x*i0.w + wv.y*i1.w + wv.z*i2.w + wv.w*i3.w;
            }
        }
    }
    #pragma unroll
    for (int j = 0; j < 4; ++j) {
        size_t ob = (size_t)(og*4 + j) * P_ + hw0 + pg*4;
        float4 rv = *(const float4*)(res + ob);
        float4 r = acc[j];
        r.x += rv.x; r.y += rv.y; r.z += rv.z; r.w += rv.w;
        *(float4*)(out + ob) = r;
    }
}

// ------- depthwise 3x3 + bias, fused l2norm over w for channels < 128 ------
__global__ __launch_bounds__(256) void dwrow_norm_kernel(const float* __restrict__ in,
        const float* __restrict__ w9, const float* __restrict__ bias,
        float* __restrict__ out) {
    int h = blockIdx.x, o = blockIdx.y;
    int w = threadIdx.x;
    const float* ip = in + ((size_t)o << 16);
    const float* wp = w9 + o * 9;
    float acc = bias[o];
    #pragma unroll
    for (int dy = -1; dy <= 1; ++dy) {
        int hh = h + dy;
        if (hh < 0 || hh > 255) continue;
        const float* row = ip + hh*256;
        #pragma unroll
        for (int dx = -1; dx <= 1; ++dx) {
            int ww = w + dx;
            if (ww < 0 || ww > 255) continue;
            acc += wp[(dy+1)*3 + (dx+1)] * row[ww];
        }
    }
    if (o < 128) {
        float s = acc * acc;
        #pragma unroll
        for (int off = 32; off; off >>= 1) s += __shfl_down(s, off, 64);
        __shared__ float red[4];
        int wv = w >> 6, ln = w & 63;
        if (ln == 0) red[wv] = s;
        __syncthreads();
        float tot = red[0] + red[1] + red[2] + red[3];
        acc *= 1.0f / fmaxf(sqrtf(tot), 1e-12f);
    }
    out[((size_t)o << 16) + h*256 + w] = acc;
}

// ---------------- plain depthwise 3x3 + bias (stage B) ----------------------
__global__ __launch_bounds__(256) void dwconv_kernel(const float* __restrict__ in,
        const float* __restrict__ w9, const float* __restrict__ bias,
        float* __restrict__ out) {
    size_t t = (size_t)blockIdx.x * 256 + threadIdx.x;
    int hw = (int)(t & 65535);
    int o = (int)(t >> 16);
    int h = hw >> 8, w = hw & 255;
    const float* ip = in + ((size_t)o << 16);
    const float* wp = w9 + o * 9;
    float acc = bias[o];
    #pragma unroll
    for (int dy = -1; dy <= 1; ++dy) {
        int hh = h + dy;
        if (hh < 0 || hh > 255) continue;
        #pragma unroll
        for (int dx = -1; dx <= 1; ++dx) {
            int ww = w + dx;
            if (ww < 0 || ww > 255) continue;
            acc += wp[(dy+1)*3 + (dx+1)] * ip[hh*256 + ww];
        }
    }
    out[t] = acc;
}

// ---------------- FFN depthwise 3x3 fused with exact-GELU gate --------------
__global__ __launch_bounds__(256) void ffn_dw_kernel(const float* __restrict__ hid,
        const float* __restrict__ w9, const float* __restrict__ bias,
        float* __restrict__ g) {
    size_t t = (size_t)blockIdx.x * 256 + threadIdx.x;   // 170*P_ threads
    int hw = (int)(t & 65535);
    int i = (int)(t >> 16);
    int h = hw >> 8, w = hw & 255;
    const float* ip1 = hid + ((size_t)i << 16);
    const float* ip2 = ip1 + ((size_t)170 << 16);
    const float* wp1 = w9 + i * 9;
    const float* wp2 = w9 + (i + 170) * 9;
    float a = bias[i], b2 = bias[i + 170];
    #pragma unroll
    for (int dy = -1; dy <= 1; ++dy) {
        int hh = h + dy;
        if (hh < 0 || hh > 255) continue;
        #pragma unroll
        for (int dx = -1; dx <= 1; ++dx) {
            int ww = w + dx;
            if (ww < 0 || ww > 255) continue;
            int off = hh*256 + ww;
            int ki = (dy+1)*3 + (dx+1);
            a  += wp1[ki] * ip1[off];
            b2 += wp2[ki] * ip2[off];
        }
    }
    float ge = 0.5f * a * (1.0f + erff(a * 0.70710678118654752440f));
    g[t] = ge * b2;
}

// ---------------- l2 normalize over (c,w), per (q|k, h) ---------------------
__global__ __launch_bounds__(256) void l2norm_h_kernel(float* __restrict__ dw) {
    int h = blockIdx.x, qk = blockIdx.y;
    float* base = dw + ((size_t)(qk*64) << 16) + h*256;
    int tid = threadIdx.x;
    float s = 0.f;
    for (int idx = tid; idx < 16384; idx += 256) {
        int c = idx >> 8, w = idx & 255;
        float v = base[((size_t)c << 16) + w];
        s += v * v;
    }
    #pragma unroll
    for (int off = 32; off; off >>= 1) s += __shfl_down(s, off, 64);
    __shared__ float red[4];
    int wv = tid >> 6, ln = tid & 63;
    if (ln == 0) red[wv] = s;
    __syncthreads();
    float tot = red[0] + red[1] + red[2] + red[3];
    float inv = 1.0f / fmaxf(sqrtf(tot), 1e-12f);
    for (int idx = tid; idx < 16384; idx += 256) {
        int c = idx >> 8, w = idx & 255;
        base[((size_t)c << 16) + w] *= inv;
    }
}

// ---------------------------------------------------------------------------
extern "C" void kernel_launch(void* const* d_in, const int* in_sizes, int n_in,
                              void* d_out, int out_size, void* d_ws, size_t ws_size,
                              hipStream_t stream) {
    (void)in_sizes; (void)n_in; (void)out_size; (void)ws_size;
    const float* x = (const float*)d_in[0];
    float* ws  = (float*)d_ws;
    float* out = (float*)d_out;
    float* DW   = ws + DW_OFF;
    float* QKV  = ws + QKV_OFF;
    float* ATTP = ws + ATTP_OFF;   // aliases QKV (dead by the time it's used)
    float* Y    = ws + Y_OFF;
    float* ATT  = ws + ATT_OFF;
    float* HID  = ws + HID_OFF;
    float* G    = ws + G_OFF;

    for (int b = 0; b < 4; ++b) {
        const float* xb = x + (size_t)b * 64 * P_;
        float* outb = out + (size_t)b * 64 * P_;

        // ===== stage A: attention over W (wxw); m -> d_out =====
        conv64_kernel<192,true,false><<<1024, 256, 0, stream>>>(xb,
                (const float*)d_in[2], (const float*)d_in[3],
                (const float*)d_in[4], (const float*)d_in[5], QKV, nullptr);
        dwrow_norm_kernel<<<dim3(256,192), 256, 0, stream>>>(QKV,
                (const float*)d_in[6], (const float*)d_in[7], DW);
        attn_gemm_kernel<false><<<dim3(4,64), 256, 0, stream>>>(DW, ATTP);
        softmax_kernel<<<256, 256, 0, stream>>>(ATTP, (const float*)d_in[10], ATT);
        av_w_kernel<<<dim3(128,2), 256, 0, stream>>>(DW, ATT, Y);
        conv64_kernel<64,false,true><<<1024, 256, 0, stream>>>(Y,
                nullptr, nullptr,
                (const float*)d_in[8], (const float*)d_in[9], outb, xb);

        // ===== stage B: attention over H (hxh); z -> d_out =====
        conv64_kernel<192,true,false><<<1024, 256, 0, stream>>>(outb,
                (const float*)d_in[11], (const float*)d_in[12],
                (const float*)d_in[13], (const float*)d_in[14], QKV, nullptr);
        dwconv_kernel<<<49152, 256, 0, stream>>>(QKV, (const float*)d_in[15],
                (const float*)d_in[16], DW);
        l2norm_h_kernel<<<dim3(256,2), 256, 0, stream>>>(DW);
        attn_gemm_kernel<true><<<dim3(4,64), 256, 0, stream>>>(DW, ATTP);
        softmax_kernel<<<256, 256, 0, stream>>>(ATTP, (const float*)d_in[19], ATT);
        av_h_kernel<<<dim3(128,2), 256, 0, stream>>>(DW, ATT, Y);
        conv64_kernel<64,false,true><<<1024, 256, 0, stream>>>(Y,
                nullptr, nullptr,
                (const float*)d_in[17], (const float*)d_in[18], outb, outb);

        // ===== stage C: gated FFN; z + ffn -> d_out =====
        conv64_kernel<340,true,false><<<1024, 256, 0, stream>>>(outb,
                (const float*)d_in[20], (const float*)d_in[21],
                (const float*)d_in[22], (const float*)d_in[23], HID, nullptr);
        ffn_dw_kernel<<<43520, 256, 0, stream>>>(HID, (const float*)d_in[24],
                (const float*)d_in[25], G);
        conv170_kernel<<<1024, 256, 0, stream>>>(G, (const float*)d_in[26],
                (const float*)d_in[27], outb, outb);
    }
}

// Round 5
// 2413.815 us; speedup vs baseline: 2.0084x; 1.1878x over previous
//
#include <hip/hip_runtime.h>
#include <math.h>
#include <stdint.h>

// Problem constants (per batch): C=64, H=W=256, P=65536 pixels.
#define P_ 65536

// ---- per-batch workspace layout (float offsets). Peak = 33,423,360 floats
// ---- = 127.5 MiB (identical to round-2/3/4 known-good footprint).
#define DW_OFF   0ul            // 192*P (q,k,v post-dwconv)
#define QKV_OFF  12582912ul     // 192*P (pre-dwconv)  [dead after dwconv]
#define ATTP_OFF QKV_OFF        // 64*P K-split partials ALIAS dead QKV region
#define Y_OFF    25165824ul     // 64*P  (attn out)
#define ATT_OFF  31457280ul     // P     (softmaxed attention)
// stage C overlays:
#define HID_OFF  0ul            // 340*P
#define G_OFF    22282240ul     // 170*P

typedef __attribute__((ext_vector_type(8))) short bf16x8;   // 8 bf16 in 4 VGPRs
typedef __attribute__((ext_vector_type(4))) float f32x4;

__device__ __forceinline__ unsigned short f2bf(float f) {   // RNE fp32->bf16
    uint32_t u = __float_as_uint(f);
    return (unsigned short)((u + 0x7FFFu + ((u >> 16) & 1u)) >> 16);
}
__device__ __forceinline__ float bf2f(unsigned short h) {
    return __uint_as_float((uint32_t)h << 16);
}

// ============== MFMA 1x1 conv: out[o,p] = sum_c W[o,c]*X[c,p] ===============
// 64-pixel tile per block, 256 threads = 4 waves. Wave w owns px-tile w (16
// px); loops over 4 o-tiles per 64-o chunk. LDS bf16 [px][c] / [o][c] with
// 16B k-blocks XOR-swizzled by (row&7) -> 2-way bank aliasing (free).
// A-frag: A[m=lane&15][k=quad*8+j]; B-frag: B[k=quad*8+j][n=lane&15];
// D: row=(quad*4+reg) (o), col=lane&15 (px). fp32 epilogue: +bias [+res].
template<int CIN, int CPAD, int COUT, bool LN, bool RES>
__global__ __launch_bounds__(256) void conv_mfma_kernel(
        const float* __restrict__ in, const float* __restrict__ lnw,
        const float* __restrict__ lnb, const float* __restrict__ Wt,
        const float* __restrict__ bias, float* __restrict__ out,
        const float* __restrict__ res) {
    constexpr int NSL = CPAD / 32;           // K slices of 32
    __shared__ unsigned short sX[64 * CPAD];
    __shared__ unsigned short sW[64 * CPAD];
    __shared__ float sPa[256], sPb[256], sMu[64], sInv[64];
    int tid = threadIdx.x;
    int hw0 = blockIdx.x * 64;
    int lane = tid & 63, wave = tid >> 6;

    {   // ---- stage X: fp32 global -> bf16 swizzled LDS [px][c] ----
        uint32_t* sX32 = (uint32_t*)sX;
        #pragma unroll
        for (int it = 0; it < CPAD / 8; ++it) {
            int idx = tid + it * 256;
            int p = idx & 63, c = (idx >> 6) * 2;
            float v0 = (c < CIN)     ? in[(size_t)c * P_ + hw0 + p]     : 0.f;
            float v1 = (c + 1 < CIN) ? in[(size_t)(c+1) * P_ + hw0 + p] : 0.f;
            uint32_t pk = (uint32_t)f2bf(v0) | ((uint32_t)f2bf(v1) << 16);
            int kb = c >> 3;
            sX32[(p * CPAD + (((kb ^ (p & 7)) << 3) | (c & 7))) >> 1] = pk;
        }
    }
    __syncthreads();
    if constexpr (LN) {                      // per-pixel LN over 64 channels
        int p = tid & 63, q = tid >> 6;
        float s = 0.f, s2 = 0.f;
        #pragma unroll
        for (int c = q * 16; c < q * 16 + 16; ++c) {
            float v = bf2f(sX[p * 64 + ((((c >> 3) ^ (p & 7)) << 3) | (c & 7))]);
            s += v; s2 += v * v;
        }
        sPa[tid] = s; sPb[tid] = s2;
        __syncthreads();
        if (tid < 64) {
            float ss = sPa[tid] + sPa[tid+64] + sPa[tid+128] + sPa[tid+192];
            float qq = sPb[tid] + sPb[tid+64] + sPb[tid+128] + sPb[tid+192];
            float mu = ss * (1.f/64.f);
            float var = qq * (1.f/64.f) - mu * mu;
            sMu[tid] = mu; sInv[tid] = rsqrtf(var + 1e-5f);
        }
        __syncthreads();
        float mu = sMu[p], inv = sInv[p];
        #pragma unroll
        for (int c = q * 16; c < q * 16 + 16; ++c) {
            int sw = p * 64 + ((((c >> 3) ^ (p & 7)) << 3) | (c & 7));
            float v = bf2f(sX[sw]);
            sX[sw] = f2bf((v - mu) * inv * lnw[c] + lnb[c]);
        }
        __syncthreads();
    }

    int pxl = lane & 15, quad = lane >> 4;
    int pgl = hw0 + wave * 16 + pxl;         // this lane's global pixel
    for (int o0 = 0; o0 < COUT; o0 += 64) {
        __syncthreads();                     // previous chunk's sW reads done
        {   // ---- stage weight chunk: [o][c] bf16 swizzled ----
            uint32_t* sW32 = (uint32_t*)sW;
            #pragma unroll
            for (int it = 0; it < CPAD / 8; ++it) {
                int idx = tid + it * 256;
                int c2 = idx % (CPAD / 2), o = idx / (CPAD / 2);
                int c = c2 * 2, og = o0 + o;
                float v0 = (og < COUT && c < CIN)     ? Wt[(size_t)og * CIN + c]     : 0.f;
                float v1 = (og < COUT && c + 1 < CIN) ? Wt[(size_t)og * CIN + c + 1] : 0.f;
                uint32_t pk = (uint32_t)f2bf(v0) | ((uint32_t)f2bf(v1) << 16);
                int kb = c >> 3;
                sW32[(o * CPAD + (((kb ^ (o & 7)) << 3) | (c & 7))) >> 1] = pk;
            }
        }
        __syncthreads();
        f32x4 acc[4];
        #pragma unroll
        for (int ot = 0; ot < 4; ++ot) acc[ot] = (f32x4){0.f, 0.f, 0.f, 0.f};
        #pragma unroll
        for (int s = 0; s < NSL; ++s) {
            int p = wave * 16 + pxl;
            int kb = s * 4 + quad;
            bf16x8 bfrag = *(const bf16x8*)&sX[p * CPAD + ((kb ^ (p & 7)) << 3)];
            #pragma unroll
            for (int ot = 0; ot < 4; ++ot) {
                int o = ot * 16 + pxl;
                bf16x8 afrag = *(const bf16x8*)&sW[o * CPAD + ((kb ^ (o & 7)) << 3)];
                acc[ot] = __builtin_amdgcn_mfma_f32_16x16x32_bf16(afrag, bfrag, acc[ot], 0, 0, 0);
            }
        }
        #pragma unroll
        for (int ot = 0; ot < 4; ++ot) {
            #pragma unroll
            for (int r = 0; r < 4; ++r) {
                int og = o0 + ot * 16 + quad * 4 + r;
                if (COUT % 64 == 0 || og < COUT) {
                    size_t ob = (size_t)og * P_ + pgl;
                    float v = acc[ot][r] + bias[og];
                    if constexpr (RES) v += res[ob];
                    out[ob] = v;
                }
            }
        }
    }
}

// ============ unified 128x128-tile fp32 GEMM core, 8x8 micro-tile ===========
#define GEMM_ACC_DECL float4 acc[8][2]; \
    _Pragma("unroll") for (int a_ = 0; a_ < 8; ++a_) { \
        acc[a_][0] = make_float4(0.f,0.f,0.f,0.f); \
        acc[a_][1] = make_float4(0.f,0.f,0.f,0.f); }

__device__ __forceinline__ void gemm_inner16(const float* As, const float* Bs,
        int tx, int ty, float4 acc[8][2]) {
    const float4* As4 = (const float4*)As;
    const float4* Bs4 = (const float4*)Bs;
    #pragma unroll
    for (int kk = 0; kk < 16; ++kk) {
        float4 a0 = As4[kk*33 + ty*2];
        float4 a1 = As4[kk*33 + ty*2 + 1];
        float4 b0 = Bs4[kk*33 + tx*2];
        float4 b1 = Bs4[kk*33 + tx*2 + 1];
        float av[8] = {a0.x,a0.y,a0.z,a0.w,a1.x,a1.y,a1.z,a1.w};
        #pragma unroll
        for (int a = 0; a < 8; ++a) {
            acc[a][0].x += av[a]*b0.x; acc[a][0].y += av[a]*b0.y;
            acc[a][0].z += av[a]*b0.z; acc[a][0].w += av[a]*b0.w;
            acc[a][1].x += av[a]*b1.x; acc[a][1].y += av[a]*b1.y;
            acc[a][1].z += av[a]*b1.z; acc[a][1].w += av[a]*b1.w;
        }
    }
}

// ---- attention logits: part[ks][i][j] over one channel ks ------------------
template<bool RCONTIG>
__global__ __launch_bounds__(256) void attn_gemm_kernel(const float* __restrict__ dw,
        float* __restrict__ part) {
    __shared__ float As[16*132], Bs[16*132];
    int tid = threadIdx.x, tx = tid & 15, ty = tid >> 4;
    int i0 = (blockIdx.x & 1) * 128, j0 = (blockIdx.x >> 1) * 128;
    int ks = blockIdx.y;
    const float* qc = dw + ((size_t)ks << 16);
    const float* kc = dw + ((size_t)(64 + ks) << 16);
    GEMM_ACC_DECL
    for (int r0 = 0; r0 < 256; r0 += 16) {
        __syncthreads();
        #pragma unroll
        for (int rep = 0; rep < 8; ++rep) {
            int idx = tid + rep * 256;
            if (RCONTIG) {
                int ii = idx >> 4, rr = idx & 15;
                As[rr*132 + ii] = qc[(i0+ii)*256 + r0+rr];
                Bs[rr*132 + ii] = kc[(j0+ii)*256 + r0+rr];
            } else {
                int rr = idx >> 7, ii = idx & 127;
                As[rr*132 + ii] = qc[(r0+rr)*256 + i0+ii];
                Bs[rr*132 + ii] = kc[(r0+rr)*256 + j0+ii];
            }
        }
        __syncthreads();
        gemm_inner16(As, Bs, tx, ty, acc);
    }
    float* pb = part + (size_t)ks * 65536;
    #pragma unroll
    for (int a = 0; a < 8; ++a) {
        float* row = pb + (size_t)(i0 + ty*8 + a) * 256 + j0 + tx*8;
        *(float4*)row = acc[a][0];
        *(float4*)(row + 4) = acc[a][1];
    }
}

// ---- av_w as GEMM: Out[(h,c), u] = sum_w V[c,h,w] * Att[w,u] ---------------
__global__ __launch_bounds__(256) void av_w_kernel(const float* __restrict__ dw,
        const float* __restrict__ att, float* __restrict__ out) {
    __shared__ float As[16*132], Bs[16*132];
    int tid = threadIdx.x, tx = tid & 15, ty = tid >> 4;
    int m0 = blockIdx.x * 128;
    int u0 = blockIdx.y * 128;
    GEMM_ACC_DECL
    for (int w0 = 0; w0 < 256; w0 += 16) {
        __syncthreads();
        #pragma unroll
        for (int rep = 0; rep < 8; ++rep) {
            int idx = tid + rep * 256;
            {   int mm = idx >> 4, wl = idx & 15;
                int m = m0 + mm, c = m & 63, h = m >> 6;
                As[wl*132 + mm] = dw[((size_t)(128+c) << 16) + h*256 + w0+wl];
            }
            {   int wl = idx >> 7, uu = idx & 127;
                Bs[wl*132 + uu] = att[(w0+wl)*256 + u0+uu];
            }
        }
        __syncthreads();
        gemm_inner16(As, Bs, tx, ty, acc);
    }
    #pragma unroll
    for (int a = 0; a < 8; ++a) {
        int m = m0 + ty*8 + a, c = m & 63, h = m >> 6;
        float* row = out + ((size_t)c << 16) + h*256 + u0 + tx*8;
        *(float4*)row = acc[a][0];
        *(float4*)(row + 4) = acc[a][1];
    }
}

// ---- av_h as GEMM: Out[(c,w), h] = sum_g V[c,g,w] * Att[h,g] ---------------
__global__ __launch_bounds__(256) void av_h_kernel(const float* __restrict__ dw,
        const float* __restrict__ att, float* __restrict__ out) {
    __shared__ float As[16*132], Bs[16*132];
    int tid = threadIdx.x, tx = tid & 15, ty = tid >> 4;
    int c = blockIdx.x >> 1;
    int w0 = (blockIdx.x & 1) * 128;
    int h0 = blockIdx.y * 128;
    const float* vc = dw + ((size_t)(128 + c) << 16);
    GEMM_ACC_DECL
    for (int g0 = 0; g0 < 256; g0 += 16) {
        __syncthreads();
        #pragma unroll
        for (int rep = 0; rep < 8; ++rep) {
            int idx = tid + rep * 256;
            {   int hh = idx >> 4, gl = idx & 15;
                As[gl*132 + hh] = att[(h0+hh)*256 + g0+gl];
            }
            {   int gl = idx >> 7, mm = idx & 127;
                Bs[gl*132 + mm] = vc[(g0+gl)*256 + w0+mm];
            }
        }
        __syncthreads();
        gemm_inner16(As, Bs, tx, ty, acc);
    }
    #pragma unroll
    for (int a = 0; a < 8; ++a) {
        int h = h0 + ty*8 + a;
        float* row = out + ((size_t)c << 16) + h*256 + w0 + tx*8;
        *(float4*)row = acc[a][0];
        *(float4*)(row + 4) = acc[a][1];
    }
}

// ---------------- sum 64 K-split partials, scale by temp, softmax row -------
__global__ __launch_bounds__(256) void softmax_kernel(const float* __restrict__ part,
        const float* __restrict__ temp, float* __restrict__ att) {
    int i = blockIdx.x;
    int j = threadIdx.x;
    size_t rowoff = (size_t)i * 256 + j;
    float s = 0.f;
    #pragma unroll
    for (int kk = 0; kk < 64; ++kk) s += part[(size_t)kk * 65536 + rowoff];
    s *= temp[0];
    __shared__ float redA[4], redB[4];
    int wv = j >> 6, ln = j & 63;
    float m = s;
    #pragma unroll
    for (int off = 32; off; off >>= 1) m = fmaxf(m, __shfl_down(m, off, 64));
    if (ln == 0) redA[wv] = m;
    __syncthreads();
    m = fmaxf(fmaxf(redA[0], redA[1]), fmaxf(redA[2], redA[3]));
    float e = expf(s - m);
    float t2 = e;
    #pragma unroll
    for (int off = 32; off; off >>= 1) t2 += __shfl_down(t2, off, 64);
    if (ln == 0) redB[wv] = t2;
    __syncthreads();
    float tot = redB[0] + redB[1] + redB[2] + redB[3];
    att[rowoff] = e / tot;
}

// ------- depthwise 3x3 + bias, fused l2norm over w for channels < 128 ------
__global__ __launch_bounds__(256) void dwrow_norm_kernel(const float* __restrict__ in,
        const float* __restrict__ w9, const float* __restrict__ bias,
        float* __restrict__ out) {
    int h = blockIdx.x, o = blockIdx.y;
    int w = threadIdx.x;
    const float* ip = in + ((size_t)o << 16);
    const float* wp = w9 + o * 9;
    float acc = bias[o];
    #pragma unroll
    for (int dy = -1; dy <= 1; ++dy) {
        int hh = h + dy;
        if (hh < 0 || hh > 255) continue;
        const float* row = ip + hh*256;
        #pragma unroll
        for (int dx = -1; dx <= 1; ++dx) {
            int ww = w + dx;
            if (ww < 0 || ww > 255) continue;
            acc += wp[(dy+1)*3 + (dx+1)] * row[ww];
        }
    }
    if (o < 128) {
        float s = acc * acc;
        #pragma unroll
        for (int off = 32; off; off >>= 1) s += __shfl_down(s, off, 64);
        __shared__ float red[4];
        int wv = w >> 6, ln = w & 63;
        if (ln == 0) red[wv] = s;
        __syncthreads();
        float tot = red[0] + red[1] + red[2] + red[3];
        acc *= 1.0f / fmaxf(sqrtf(tot), 1e-12f);
    }
    out[((size_t)o << 16) + h*256 + w] = acc;
}

// ---------------- plain depthwise 3x3 + bias (stage B) ----------------------
__global__ __launch_bounds__(256) void dwconv_kernel(const float* __restrict__ in,
        const float* __restrict__ w9, const float* __restrict__ bias,
        float* __restrict__ out) {
    size_t t = (size_t)blockIdx.x * 256 + threadIdx.x;
    int hw = (int)(t & 65535);
    int o = (int)(t >> 16);
    int h = hw >> 8, w = hw & 255;
    const float* ip = in + ((size_t)o << 16);
    const float* wp = w9 + o * 9;
    float acc = bias[o];
    #pragma unroll
    for (int dy = -1; dy <= 1; ++dy) {
        int hh = h + dy;
        if (hh < 0 || hh > 255) continue;
        #pragma unroll
        for (int dx = -1; dx <= 1; ++dx) {
            int ww = w + dx;
            if (ww < 0 || ww > 255) continue;
            acc += wp[(dy+1)*3 + (dx+1)] * ip[hh*256 + ww];
        }
    }
    out[t] = acc;
}

// ---------------- FFN depthwise 3x3 fused with exact-GELU gate --------------
__global__ __launch_bounds__(256) void ffn_dw_kernel(const float* __restrict__ hid,
        const float* __restrict__ w9, const float* __restrict__ bias,
        float* __restrict__ g) {
    size_t t = (size_t)blockIdx.x * 256 + threadIdx.x;   // 170*P_ threads
    int hw = (int)(t & 65535);
    int i = (int)(t >> 16);
    int h = hw >> 8, w = hw & 255;
    const float* ip1 = hid + ((size_t)i << 16);
    const float* ip2 = ip1 + ((size_t)170 << 16);
    const float* wp1 = w9 + i * 9;
    const float* wp2 = w9 + (i + 170) * 9;
    float a = bias[i], b2 = bias[i + 170];
    #pragma unroll
    for (int dy = -1; dy <= 1; ++dy) {
        int hh = h + dy;
        if (hh < 0 || hh > 255) continue;
        #pragma unroll
        for (int dx = -1; dx <= 1; ++dx) {
            int ww = w + dx;
            if (ww < 0 || ww > 255) continue;
            int off = hh*256 + ww;
            int ki = (dy+1)*3 + (dx+1);
            a  += wp1[ki] * ip1[off];
            b2 += wp2[ki] * ip2[off];
        }
    }
    float ge = 0.5f * a * (1.0f + erff(a * 0.70710678118654752440f));
    g[t] = ge * b2;
}

// ---------------- l2 normalize over (c,w), per (q|k, h) ---------------------
__global__ __launch_bounds__(256) void l2norm_h_kernel(float* __restrict__ dw) {
    int h = blockIdx.x, qk = blockIdx.y;
    float* base = dw + ((size_t)(qk*64) << 16) + h*256;
    int tid = threadIdx.x;
    float s = 0.f;
    for (int idx = tid; idx < 16384; idx += 256) {
        int c = idx >> 8, w = idx & 255;
        float v = base[((size_t)c << 16) + w];
        s += v * v;
    }
    #pragma unroll
    for (int off = 32; off; off >>= 1) s += __shfl_down(s, off, 64);
    __shared__ float red[4];
    int wv = tid >> 6, ln = tid & 63;
    if (ln == 0) red[wv] = s;
    __syncthreads();
    float tot = red[0] + red[1] + red[2] + red[3];
    float inv = 1.0f / fmaxf(sqrtf(tot), 1e-12f);
    for (int idx = tid; idx < 16384; idx += 256) {
        int c = idx >> 8, w = idx & 255;
        base[((size_t)c << 16) + w] *= inv;
    }
}

// ---------------------------------------------------------------------------
extern "C" void kernel_launch(void* const* d_in, const int* in_sizes, int n_in,
                              void* d_out, int out_size, void* d_ws, size_t ws_size,
                              hipStream_t stream) {
    (void)in_sizes; (void)n_in; (void)out_size; (void)ws_size;
    const float* x = (const float*)d_in[0];
    float* ws  = (float*)d_ws;
    float* out = (float*)d_out;
    float* DW   = ws + DW_OFF;
    float* QKV  = ws + QKV_OFF;
    float* ATTP = ws + ATTP_OFF;   // aliases QKV (dead by the time it's used)
    float* Y    = ws + Y_OFF;
    float* ATT  = ws + ATT_OFF;
    float* HID  = ws + HID_OFF;
    float* G    = ws + G_OFF;

    for (int b = 0; b < 4; ++b) {
        const float* xb = x + (size_t)b * 64 * P_;
        float* outb = out + (size_t)b * 64 * P_;

        // ===== stage A: attention over W (wxw); m -> d_out =====
        conv_mfma_kernel<64,64,192,true,false><<<1024, 256, 0, stream>>>(xb,
                (const float*)d_in[2], (const float*)d_in[3],
                (const float*)d_in[4], (const float*)d_in[5], QKV, nullptr);
        dwrow_norm_kernel<<<dim3(256,192), 256, 0, stream>>>(QKV,
                (const float*)d_in[6], (const float*)d_in[7], DW);
        attn_gemm_kernel<false><<<dim3(4,64), 256, 0, stream>>>(DW, ATTP);
        softmax_kernel<<<256, 256, 0, stream>>>(ATTP, (const float*)d_in[10], ATT);
        av_w_kernel<<<dim3(128,2), 256, 0, stream>>>(DW, ATT, Y);
        conv_mfma_kernel<64,64,64,false,true><<<1024, 256, 0, stream>>>(Y,
                nullptr, nullptr,
                (const float*)d_in[8], (const float*)d_in[9], outb, xb);

        // ===== stage B: attention over H (hxh); z -> d_out =====
        conv_mfma_kernel<64,64,192,true,false><<<1024, 256, 0, stream>>>(outb,
                (const float*)d_in[11], (const float*)d_in[12],
                (const float*)d_in[13], (const float*)d_in[14], QKV, nullptr);
        dwconv_kernel<<<49152, 256, 0, stream>>>(QKV, (const float*)d_in[15],
                (const float*)d_in[16], DW);
        l2norm_h_kernel<<<dim3(256,2), 256, 0, stream>>>(DW);
        attn_gemm_kernel<true><<<dim3(4,64), 256, 0, stream>>>(DW, ATTP);
        softmax_kernel<<<256, 256, 0, stream>>>(ATTP, (const float*)d_in[19], ATT);
        av_h_kernel<<<dim3(128,2), 256, 0, stream>>>(DW, ATT, Y);
        conv_mfma_kernel<64,64,64,false,true><<<1024, 256, 0, stream>>>(Y,
                nullptr, nullptr,
                (const float*)d_in[17], (const float*)d_in[18], outb, outb);

        // ===== stage C: gated FFN; z + ffn -> d_out =====
        conv_mfma_kernel<64,64,340,true,false><<<1024, 256, 0, stream>>>(outb,
                (const float*)d_in[20], (const float*)d_in[21],
                (const float*)d_in[22], (const float*)d_in[23], HID, nullptr);
        ffn_dw_kernel<<<43520, 256, 0, stream>>>(HID, (const float*)d_in[24],
                (const float*)d_in[25], G);
        conv_mfma_kernel<170,192,64,false,true><<<1024, 256, 0, stream>>>(G,
                nullptr, nullptr,
                (const float*)d_in[26], (const float*)d_in[27], outb, outb);
    }
}